// Round 13
// baseline (164.627 us; speedup 1.0000x reference)
//
#include <hip/hip_runtime.h>
#include <hip/hip_bf16.h>
#include <math.h>

#define BB   2
#define NPTS 16384
#define KNB  16
#define DPTS 64
#define DM   128

typedef float  f32x4  __attribute__((ext_vector_type(4)));
typedef short  bf16x8 __attribute__((ext_vector_type(8)));

__device__ __forceinline__ unsigned short f2bf(float f) {
    union { __hip_bfloat16 h; unsigned short u; } v;
    v.h = __float2bfloat16(f);
    return v.u;
}
__device__ __forceinline__ float bf2f(unsigned short h) {
    union { unsigned u; float f; } v; v.u = ((unsigned)h) << 16;
    return v.f;
}

// LDS tile: 64 rows x 128 bf16, XOR-swizzled; keeps 16B vectors contiguous.
__device__ __forceinline__ int swz(int row, int col) {
    return row * DM + (col ^ ((row & 7) << 3));
}

// wbf layout (bf16 elems): [dw2 16K | gw1 16K | gw2 16K | wq 16K | wk 16K | wv 16K | fc1_w 8K]
#define WOFF_DW2  0
#define WOFF_GW1  16384
#define WOFF_GW2  32768
#define WOFF_WQ   49152
#define WOFF_WK   65536
#define WOFF_WV   81920
#define WOFF_FC1  98304
#define WTOT      106496

// ============ Kernel 0: one-shot weight conversion f32 -> bf16 ============
__global__ __launch_bounds__(256) void cvtw_kernel(
    const float* __restrict__ dw2, const float* __restrict__ gw1,
    const float* __restrict__ gw2, const float* __restrict__ wq,
    const float* __restrict__ wk, const float* __restrict__ wv,
    const float* __restrict__ fc1_w, unsigned short* __restrict__ wb)
{
    const int i = blockIdx.x * 256 + threadIdx.x;
    if (i >= WTOT) return;
    float v;
    if (i < WOFF_WQ) {
        const int which = i >> 14, off = i & 16383;
        v = (which == 0) ? dw2[off] : (which == 1) ? gw1[off] : gw2[off];
    } else if (i < WOFF_FC1) {
        const int j = i - WOFF_WQ;
        const int which = j >> 14, off = j & 16383;
        v = (which == 0) ? wq[off] : (which == 1) ? wk[off] : wv[off];
    } else {
        v = fc1_w[i - WOFF_FC1];
    }
    wb[i] = f2bf(v);
}

// shared GEMM helper: 64x128 swizzled act tile vs bf16 weights [128][128],
// 32-col strip per wave
__device__ __forceinline__ void mfma_gemm(const unsigned short* __restrict__ AB,
                                          const unsigned short* __restrict__ Wb,
                                          int lane, int wbase, f32x4 acc[4][2])
{
    const int c = lane & 15, g = lane >> 4;
    bf16x8 Bf[2][4];
#pragma unroll
    for (int ct = 0; ct < 2; ++ct)
#pragma unroll
        for (int ks = 0; ks < 4; ++ks)
            Bf[ct][ks] = *(const bf16x8*)&Wb[(wbase + ct * 16 + c) * DM + ks * 32 + g * 8];
#pragma unroll
    for (int rt = 0; rt < 4; ++rt) {
        bf16x8 Af[4];
#pragma unroll
        for (int ks = 0; ks < 4; ++ks)
            Af[ks] = *(const bf16x8*)&AB[swz(rt * 16 + c, ks * 32 + g * 8)];
#pragma unroll
        for (int ct = 0; ct < 2; ++ct)
#pragma unroll
            for (int ks = 0; ks < 4; ++ks)
                acc[rt][ct] = __builtin_amdgcn_mfma_f32_16x16x32_bf16(
                    Af[ks], Bf[ct][ks], acc[rt][ct], 0, 0, 0);
    }
}

// ============ Kernel 1: x = fc1(features); q / (k|v interleaved) ==========
#define P_MT  64
#define FSTR  72

__global__ __launch_bounds__(256, 4) void proj_kernel(
    const float* __restrict__ features, const float* __restrict__ fc1_b,
    const unsigned short* __restrict__ wbf,
    unsigned short* __restrict__ qws, unsigned short* __restrict__ kvws)
{
    __shared__ __align__(16) unsigned short FB[P_MT * FSTR];   //  9216 B
    __shared__ __align__(16) unsigned short XB[P_MT * DM];     // 16384 B (swizzled)

    const int tid  = threadIdx.x;
    const int lane = tid & 63;
    const int wave = tid >> 6;
    const int wbase = wave * 32;
    const int c  = lane & 15;
    const int g  = lane >> 4;
    const int g4 = g * 4;
    const size_t gp0 = (size_t)blockIdx.x * P_MT;

    for (int i = tid; i < P_MT * 8; i += 256) {
        const int r = i >> 3, o = i & 7;
        const float4 a = *(const float4*)&features[(gp0 + r) * DPTS + o * 8];
        const float4 b = *(const float4*)&features[(gp0 + r) * DPTS + o * 8 + 4];
        bf16x8 t;
        t[0] = (short)f2bf(a.x); t[1] = (short)f2bf(a.y);
        t[2] = (short)f2bf(a.z); t[3] = (short)f2bf(a.w);
        t[4] = (short)f2bf(b.x); t[5] = (short)f2bf(b.y);
        t[6] = (short)f2bf(b.z); t[7] = (short)f2bf(b.w);
        *(bf16x8*)&FB[r * FSTR + o * 8] = t;
    }
    __syncthreads();

    // GEMM0: x = features @ fc1_w.T + fc1_b  (K=64)
    {
        const unsigned short* fw = wbf + WOFF_FC1;
        const float b0 = fc1_b[wbase + c], b1 = fc1_b[wbase + 16 + c];
        f32x4 acc[4][2];
#pragma unroll
        for (int rt = 0; rt < 4; ++rt) {
            acc[rt][0] = (f32x4)b0;
            acc[rt][1] = (f32x4)b1;
        }
        bf16x8 Bf[2][2];
#pragma unroll
        for (int ct = 0; ct < 2; ++ct)
#pragma unroll
            for (int ks = 0; ks < 2; ++ks)
                Bf[ct][ks] = *(const bf16x8*)&fw[(wbase + ct * 16 + c) * DPTS + ks * 32 + g * 8];
#pragma unroll
        for (int rt = 0; rt < 4; ++rt) {
            bf16x8 Af[2];
#pragma unroll
            for (int ks = 0; ks < 2; ++ks)
                Af[ks] = *(const bf16x8*)&FB[(rt * 16 + c) * FSTR + ks * 32 + g * 8];
#pragma unroll
            for (int ct = 0; ct < 2; ++ct)
#pragma unroll
                for (int ks = 0; ks < 2; ++ks)
                    acc[rt][ct] = __builtin_amdgcn_mfma_f32_16x16x32_bf16(
                        Af[ks], Bf[ct][ks], acc[rt][ct], 0, 0, 0);
        }
#pragma unroll
        for (int ct = 0; ct < 2; ++ct) {
            const int col = wbase + ct * 16 + c;
#pragma unroll
            for (int rt = 0; rt < 4; ++rt)
#pragma unroll
                for (int rg = 0; rg < 4; ++rg)
                    XB[swz(rt * 16 + g4 + rg, col)] = f2bf(acc[rt][ct][rg]);
        }
    }
    __syncthreads();

    // q = x@wq.T -> qws ; k = x@wk.T -> kvws[..][0:128] ; v = x@wv.T -> kvws[..][128:256]
    const unsigned short* wmat[3] = { wbf + WOFF_WQ, wbf + WOFF_WK, wbf + WOFF_WV };
#pragma unroll
    for (int m = 0; m < 3; ++m) {
        f32x4 acc[4][2];
#pragma unroll
        for (int rt = 0; rt < 4; ++rt)
#pragma unroll
            for (int ct = 0; ct < 2; ++ct) acc[rt][ct] = (f32x4)0.f;
        mfma_gemm(XB, wmat[m], lane, wbase, acc);
#pragma unroll
        for (int ct = 0; ct < 2; ++ct) {
            const int col = wbase + ct * 16 + c;
#pragma unroll
            for (int rt = 0; rt < 4; ++rt)
#pragma unroll
                for (int rg = 0; rg < 4; ++rg) {
                    const size_t row = gp0 + rt * 16 + g4 + rg;
                    unsigned short* dst = (m == 0)
                        ? &qws[row * DM + col]
                        : &kvws[row * (2 * DM) + (m == 2 ? DM : 0) + col];
                    *dst = f2bf(acc[rt][ct][rg]);
                }
        }
    }
}

// ============ Kernel 2: fused neighbor pipeline (single LDS buffer) =======
// LDS ~17.4KB -> 9 blocks/CU by LDS; (256,4) lets the compiler sit at the
// natural 64-VGPR footprint (r10/r12 compile to exactly 64) -> 8 blocks/CU
// = 32 waves, WITHOUT the forced-32-VGPR spill that killed r11.
#define K2_PTS 4
#define K2_R   (K2_PTS * KNB)   // 64 rows

__global__ __launch_bounds__(256, 4) void attn_kernel(
    const float* __restrict__ new_xyz, const float* __restrict__ grouped_xyz,
    const int* __restrict__ grouped_idx,
    const float* __restrict__ dw1, const float* __restrict__ db1,
    const float* __restrict__ db2,
    const float* __restrict__ gb1, const float* __restrict__ gb2,
    const unsigned short* __restrict__ wbf,
    const unsigned short* __restrict__ qws, const unsigned short* __restrict__ kvws,
    float* __restrict__ out)
{
    __shared__ __align__(16) unsigned short X[K2_R * DM];  // 16384 B, in-place
    __shared__ float REL[K2_R * 3];
    __shared__ int   IDX[K2_R];

    const int tid  = threadIdx.x;
    const int lane = tid & 63;
    const int wave = tid >> 6;
    const int wbase = wave * 32;
    const int c  = lane & 15;
    const int g  = lane >> 4;
    const int g4 = g * 4;
    const int rr = tid >> 4;        // row-within-group for vector phases
    const int o8 = (tid & 15) * 8;  // col octet base

    const int b   = blockIdx.x / (NPTS / K2_PTS);
    const int m0  = (blockIdx.x % (NPTS / K2_PTS)) * K2_PTS;
    const size_t gp0 = (size_t)b * NPTS + m0;
    const size_t bN  = (size_t)b * NPTS;
    const float SCL = 0.12751743342f;   // 1/sqrt(128) * log2(e)

    const unsigned short* dw2b = wbf + WOFF_DW2;
    const unsigned short* gw1b = wbf + WOFF_GW1;
    const unsigned short* gw2b = wbf + WOFF_GW2;

    // hoist dw1/db1 rows for this thread's col octet
    float wr[24], bbv[8];
    {
        const float4* wsrc = (const float4*)&dw1[o8 * 3];
#pragma unroll
        for (int t = 0; t < 6; ++t) ((float4*)wr)[t] = wsrc[t];
        const float4* bsrc = (const float4*)&db1[o8];
        ((float4*)bbv)[0] = bsrc[0];
        ((float4*)bbv)[1] = bsrc[1];
    }

    // ---- P0: idx + rel ----
    if (tid < K2_R) {
        const int p = tid >> 4, j = tid & 15;
        const size_t m = gp0 + p;
        const int mi = m0 + p;
#pragma unroll
        for (int cc = 0; cc < 3; ++cc)
            REL[tid * 3 + cc] = new_xyz[m * 3 + cc]
                              - grouped_xyz[(((size_t)b * 3 + cc) * NPTS + mi) * KNB + j];
        IDX[tid] = grouped_idx[m * KNB + j];
    }
    __syncthreads();

    // ---- prefetch q/k gathers (consumed in P3; k from interleaved kv) ----
    bf16x8 q8[4], k8[4];
#pragma unroll
    for (int it = 0; it < 4; ++it) {
        const int r = it * 16 + rr;
        q8[it] = *(const bf16x8*)&qws[(gp0 + it) * DM + o8];
        k8[it] = *(const bf16x8*)&kvws[(bN + IDX[r]) * (2 * DM) + o8];
    }

    // ---- P1: relu1 = relu(rel @ dw1.T + db1) -> X ----
#pragma unroll
    for (int it = 0; it < 4; ++it) {
        const int r = it * 16 + rr;
        const float rx = REL[r * 3 + 0], ry = REL[r * 3 + 1], rz = REL[r * 3 + 2];
        bf16x8 t;
#pragma unroll
        for (int j = 0; j < 8; ++j) {
            float v = bbv[j];
            v = fmaf(rx, wr[j * 3 + 0], v);
            v = fmaf(ry, wr[j * 3 + 1], v);
            v = fmaf(rz, wr[j * 3 + 2], v);
            t[j] = (short)f2bf(fmaxf(v, 0.f));
        }
        *(bf16x8*)&X[swz(r, o8)] = t;
    }
    __syncthreads();

    // ---- P2: pos = relu1 @ dw2.T + db2 ; f32 in regs; bf16 back into X ----
    f32x4 posr[4][2];
    {
        const float b0 = db2[wbase + c], b1 = db2[wbase + 16 + c];
#pragma unroll
        for (int rt = 0; rt < 4; ++rt) {
            posr[rt][0] = (f32x4)b0;
            posr[rt][1] = (f32x4)b1;
        }
    }
    mfma_gemm(X, dw2b, lane, wbase, posr);
    __syncthreads();   // drain: all relu1 reads complete before overwrite
#pragma unroll
    for (int ct = 0; ct < 2; ++ct) {
        const int col = wbase + ct * 16 + c;
#pragma unroll
        for (int rt = 0; rt < 4; ++rt)
#pragma unroll
            for (int rg = 0; rg < 4; ++rg)
                X[swz(rt * 16 + g4 + rg, col)] = f2bf(posr[rt][ct][rg]);
    }
    __syncthreads();

    // ---- P3: h = q - k + pos -> X (octet-owned, in place) ----
#pragma unroll
    for (int it = 0; it < 4; ++it) {
        const int r = it * 16 + rr;
        const bf16x8 p8 = *(const bf16x8*)&X[swz(r, o8)];
        bf16x8 t;
#pragma unroll
        for (int j = 0; j < 8; ++j) {
            const float hv = bf2f((unsigned short)q8[it][j])
                           - bf2f((unsigned short)k8[it][j])
                           + bf2f((unsigned short)p8[j]);
            t[j] = (short)f2bf(hv);
        }
        *(bf16x8*)&X[swz(r, o8)] = t;
    }
    __syncthreads();

    // ---- P4: g1 = relu(h @ gw1.T + gb1) -> X (drain then write) ----
    {
        f32x4 acc[4][2];
        const float b0 = gb1[wbase + c], b1 = gb1[wbase + 16 + c];
#pragma unroll
        for (int rt = 0; rt < 4; ++rt) {
            acc[rt][0] = (f32x4)b0;
            acc[rt][1] = (f32x4)b1;
        }
        mfma_gemm(X, gw1b, lane, wbase, acc);
        __syncthreads();   // drain h reads
#pragma unroll
        for (int ct = 0; ct < 2; ++ct) {
            const int col = wbase + ct * 16 + c;
#pragma unroll
            for (int rt = 0; rt < 4; ++rt)
#pragma unroll
                for (int rg = 0; rg < 4; ++rg)
                    X[swz(rt * 16 + g4 + rg, col)] = f2bf(fmaxf(acc[rt][ct][rg], 0.f));
        }
    }
    __syncthreads();

    // ---- P5: logits = (g1 @ gw2.T + gb2) * scl (regs) ----
    f32x4 lg[4][2];
#pragma unroll
    for (int rt = 0; rt < 4; ++rt)
#pragma unroll
        for (int ct = 0; ct < 2; ++ct) lg[rt][ct] = (f32x4)0.f;
    mfma_gemm(X, gw2b, lane, wbase, lg);
#pragma unroll
    for (int ct = 0; ct < 2; ++ct) {
        const int col = wbase + ct * 16 + c;
        const float bb = gb2[col];
#pragma unroll
        for (int rt = 0; rt < 4; ++rt)
#pragma unroll
            for (int rg = 0; rg < 4; ++rg)
                lg[rt][ct][rg] = (lg[rt][ct][rg] + bb) * SCL;
    }

    // ---- P6: in-register softmax + output reduce (v from interleaved kv) --
#pragma unroll
    for (int rt = 0; rt < 4; ++rt)
#pragma unroll
    for (int ct = 0; ct < 2; ++ct) {
        const int col = wbase + ct * 16 + c;
        f32x4 l = lg[rt][ct];
        float mx = fmaxf(fmaxf(l[0], l[1]), fmaxf(l[2], l[3]));
        mx = fmaxf(mx, __shfl_xor(mx, 16));
        mx = fmaxf(mx, __shfl_xor(mx, 32));
        f32x4 e;
        e[0] = __builtin_amdgcn_exp2f(l[0] - mx);
        e[1] = __builtin_amdgcn_exp2f(l[1] - mx);
        e[2] = __builtin_amdgcn_exp2f(l[2] - mx);
        e[3] = __builtin_amdgcn_exp2f(l[3] - mx);
        float s = e[0] + e[1] + e[2] + e[3];
        s += __shfl_xor(s, 16);
        s += __shfl_xor(s, 32);
        float o = 0.f;
#pragma unroll
        for (int rg = 0; rg < 4; ++rg) {
            const int row = rt * 16 + g4 + rg;
            const float vv = bf2f(kvws[(bN + IDX[row]) * (2 * DM) + DM + col])
                           + posr[rt][ct][rg];
            o = fmaf(e[rg], vv, o);
        }
        o += __shfl_xor(o, 16);
        o += __shfl_xor(o, 32);
        if (g == 0)
            out[(gp0 + rt) * DM + col] = o * __builtin_amdgcn_rcpf(s);
    }
}

// ======================= launch =======================
extern "C" void kernel_launch(void* const* d_in, const int* in_sizes, int n_in,
                              void* d_out, int out_size, void* d_ws, size_t ws_size,
                              hipStream_t stream)
{
    const float* new_xyz     = (const float*)d_in[0];
    const float* grouped_xyz = (const float*)d_in[1];
    const int*   grouped_idx = (const int*)d_in[2];
    const float* features    = (const float*)d_in[3];
    const float* fc1_w = (const float*)d_in[4];
    const float* fc1_b = (const float*)d_in[5];
    const float* wq    = (const float*)d_in[6];
    const float* wk    = (const float*)d_in[7];
    const float* wv    = (const float*)d_in[8];
    const float* dw1   = (const float*)d_in[9];
    const float* db1   = (const float*)d_in[10];
    const float* dw2   = (const float*)d_in[11];
    const float* db2   = (const float*)d_in[12];
    const float* gw1   = (const float*)d_in[13];
    const float* gb1   = (const float*)d_in[14];
    const float* gw2   = (const float*)d_in[15];
    const float* gb2   = (const float*)d_in[16];
    float* out = (float*)d_out;

    unsigned short* ws = (unsigned short*)d_ws;
    const size_t npt = (size_t)BB * NPTS * DM;
    unsigned short* qws  = ws;
    unsigned short* kvws = ws + npt;        // [row][k:128 | v:128]
    unsigned short* wbf  = ws + 3 * npt;

    cvtw_kernel<<<(WTOT + 255) / 256, 256, 0, stream>>>(
        dw2, gw1, gw2, wq, wk, wv, fc1_w, wbf);

    proj_kernel<<<(BB * NPTS) / P_MT, 256, 0, stream>>>(
        features, fc1_b, wbf, qws, kvws);

    attn_kernel<<<(BB * NPTS) / K2_PTS, 256, 0, stream>>>(
        new_xyz, grouped_xyz, grouped_idx,
        dw1, db1, db2, gb1, gb2,
        wbf, qws, kvws, out);
}

// Round 14
// 155.067 us; speedup vs baseline: 1.0616x; 1.0616x over previous
//
#include <hip/hip_runtime.h>
#include <hip/hip_bf16.h>
#include <math.h>

#define BB   2
#define NPTS 16384
#define KNB  16
#define DPTS 64
#define DM   128

typedef float  f32x4  __attribute__((ext_vector_type(4)));
typedef short  bf16x8 __attribute__((ext_vector_type(8)));

__device__ __forceinline__ unsigned short f2bf(float f) {
    union { __hip_bfloat16 h; unsigned short u; } v;
    v.h = __float2bfloat16(f);
    return v.u;
}
__device__ __forceinline__ float bf2f(unsigned short h) {
    union { unsigned u; float f; } v; v.u = ((unsigned)h) << 16;
    return v.f;
}

// LDS tile rows are 128 bf16; XOR-swizzle keeps 16B vectors contiguous.
__device__ __forceinline__ int swz(int row, int col) {
    return row * DM + (col ^ ((row & 7) << 3));
}

// wbf layout (bf16 elems): [dw2 16K | gw1 16K | gw2 16K | wq 16K | wk 16K | wv 16K | fc1_w 8K]
#define WOFF_DW2  0
#define WOFF_GW1  16384
#define WOFF_GW2  32768
#define WOFF_WQ   49152
#define WOFF_WK   65536
#define WOFF_WV   81920
#define WOFF_FC1  98304
#define WTOT      106496

// ============ Kernel 0: one-shot weight conversion f32 -> bf16 ============
__global__ __launch_bounds__(256) void cvtw_kernel(
    const float* __restrict__ dw2, const float* __restrict__ gw1,
    const float* __restrict__ gw2, const float* __restrict__ wq,
    const float* __restrict__ wk, const float* __restrict__ wv,
    const float* __restrict__ fc1_w, unsigned short* __restrict__ wb)
{
    const int i = blockIdx.x * 256 + threadIdx.x;
    if (i >= WTOT) return;
    float v;
    if (i < WOFF_WQ) {
        const int which = i >> 14, off = i & 16383;
        v = (which == 0) ? dw2[off] : (which == 1) ? gw1[off] : gw2[off];
    } else if (i < WOFF_FC1) {
        const int j = i - WOFF_WQ;
        const int which = j >> 14, off = j & 16383;
        v = (which == 0) ? wq[off] : (which == 1) ? wk[off] : wv[off];
    } else {
        v = fc1_w[i - WOFF_FC1];
    }
    wb[i] = f2bf(v);
}

// 32-col-strip GEMM over 64-row tile (proj kernel)
__device__ __forceinline__ void mfma_gemm(const unsigned short* __restrict__ AB,
                                          const unsigned short* __restrict__ Wb,
                                          int lane, int wbase, f32x4 acc[4][2])
{
    const int c = lane & 15, g = lane >> 4;
    bf16x8 Bf[2][4];
#pragma unroll
    for (int ct = 0; ct < 2; ++ct)
#pragma unroll
        for (int ks = 0; ks < 4; ++ks)
            Bf[ct][ks] = *(const bf16x8*)&Wb[(wbase + ct * 16 + c) * DM + ks * 32 + g * 8];
#pragma unroll
    for (int rt = 0; rt < 4; ++rt) {
        bf16x8 Af[4];
#pragma unroll
        for (int ks = 0; ks < 4; ++ks)
            Af[ks] = *(const bf16x8*)&AB[swz(rt * 16 + c, ks * 32 + g * 8)];
#pragma unroll
        for (int ct = 0; ct < 2; ++ct)
#pragma unroll
            for (int ks = 0; ks < 4; ++ks)
                acc[rt][ct] = __builtin_amdgcn_mfma_f32_16x16x32_bf16(
                    Af[ks], Bf[ct][ks], acc[rt][ct], 0, 0, 0);
    }
}

// 16-col-strip GEMM over 128-row tile (attn kernel, 8 row-tiles)
__device__ __forceinline__ void gemm16w(const unsigned short* __restrict__ X,
                                        const unsigned short* __restrict__ Wb,
                                        int c, int g, int wb16, f32x4 acc[8])
{
    bf16x8 Bf[4];
#pragma unroll
    for (int ks = 0; ks < 4; ++ks)
        Bf[ks] = *(const bf16x8*)&Wb[(wb16 + c) * DM + ks * 32 + g * 8];
#pragma unroll
    for (int rt = 0; rt < 8; ++rt) {
        bf16x8 Af[4];
#pragma unroll
        for (int ks = 0; ks < 4; ++ks)
            Af[ks] = *(const bf16x8*)&X[swz(rt * 16 + c, ks * 32 + g * 8)];
#pragma unroll
        for (int ks = 0; ks < 4; ++ks)
            acc[rt] = __builtin_amdgcn_mfma_f32_16x16x32_bf16(
                Af[ks], Bf[ks], acc[rt], 0, 0, 0);
    }
}

// ============ Kernel 1: x = fc1(features); q / (k|v interleaved) ==========
#define P_MT  64
#define FSTR  72

__global__ __launch_bounds__(256, 4) void proj_kernel(
    const float* __restrict__ features, const float* __restrict__ fc1_b,
    const unsigned short* __restrict__ wbf,
    unsigned short* __restrict__ qws, unsigned short* __restrict__ kvws)
{
    __shared__ __align__(16) unsigned short FB[P_MT * FSTR];
    __shared__ __align__(16) unsigned short XB[P_MT * DM];

    const int tid  = threadIdx.x;
    const int lane = tid & 63;
    const int wave = tid >> 6;
    const int wbase = wave * 32;
    const int c  = lane & 15;
    const int g  = lane >> 4;
    const int g4 = g * 4;
    const size_t gp0 = (size_t)blockIdx.x * P_MT;

    for (int i = tid; i < P_MT * 8; i += 256) {
        const int r = i >> 3, o = i & 7;
        const float4 a = *(const float4*)&features[(gp0 + r) * DPTS + o * 8];
        const float4 b = *(const float4*)&features[(gp0 + r) * DPTS + o * 8 + 4];
        bf16x8 t;
        t[0] = (short)f2bf(a.x); t[1] = (short)f2bf(a.y);
        t[2] = (short)f2bf(a.z); t[3] = (short)f2bf(a.w);
        t[4] = (short)f2bf(b.x); t[5] = (short)f2bf(b.y);
        t[6] = (short)f2bf(b.z); t[7] = (short)f2bf(b.w);
        *(bf16x8*)&FB[r * FSTR + o * 8] = t;
    }
    __syncthreads();

    // GEMM0: x = features @ fc1_w.T + fc1_b  (K=64)
    {
        const unsigned short* fw = wbf + WOFF_FC1;
        const float b0 = fc1_b[wbase + c], b1 = fc1_b[wbase + 16 + c];
        f32x4 acc[4][2];
#pragma unroll
        for (int rt = 0; rt < 4; ++rt) {
            acc[rt][0] = (f32x4)b0;
            acc[rt][1] = (f32x4)b1;
        }
        bf16x8 Bf[2][2];
#pragma unroll
        for (int ct = 0; ct < 2; ++ct)
#pragma unroll
            for (int ks = 0; ks < 2; ++ks)
                Bf[ct][ks] = *(const bf16x8*)&fw[(wbase + ct * 16 + c) * DPTS + ks * 32 + g * 8];
#pragma unroll
        for (int rt = 0; rt < 4; ++rt) {
            bf16x8 Af[2];
#pragma unroll
            for (int ks = 0; ks < 2; ++ks)
                Af[ks] = *(const bf16x8*)&FB[(rt * 16 + c) * FSTR + ks * 32 + g * 8];
#pragma unroll
            for (int ct = 0; ct < 2; ++ct)
#pragma unroll
                for (int ks = 0; ks < 2; ++ks)
                    acc[rt][ct] = __builtin_amdgcn_mfma_f32_16x16x32_bf16(
                        Af[ks], Bf[ct][ks], acc[rt][ct], 0, 0, 0);
        }
#pragma unroll
        for (int ct = 0; ct < 2; ++ct) {
            const int col = wbase + ct * 16 + c;
#pragma unroll
            for (int rt = 0; rt < 4; ++rt)
#pragma unroll
                for (int rg = 0; rg < 4; ++rg)
                    XB[swz(rt * 16 + g4 + rg, col)] = f2bf(acc[rt][ct][rg]);
        }
    }
    __syncthreads();

    // q -> qws ; k -> kvws[..][0:128] ; v -> kvws[..][128:256]
    const unsigned short* wmat[3] = { wbf + WOFF_WQ, wbf + WOFF_WK, wbf + WOFF_WV };
#pragma unroll
    for (int m = 0; m < 3; ++m) {
        f32x4 acc[4][2];
#pragma unroll
        for (int rt = 0; rt < 4; ++rt)
#pragma unroll
            for (int ct = 0; ct < 2; ++ct) acc[rt][ct] = (f32x4)0.f;
        mfma_gemm(XB, wmat[m], lane, wbase, acc);
#pragma unroll
        for (int ct = 0; ct < 2; ++ct) {
            const int col = wbase + ct * 16 + c;
#pragma unroll
            for (int rt = 0; rt < 4; ++rt)
#pragma unroll
                for (int rg = 0; rg < 4; ++rg) {
                    const size_t row = gp0 + rt * 16 + g4 + rg;
                    unsigned short* dst = (m == 0)
                        ? &qws[row * DM + col]
                        : &kvws[row * (2 * DM) + (m == 2 ? DM : 0) + col];
                    *dst = f2bf(acc[rt][ct][rg]);
                }
        }
    }
}

// ============ Kernel 2: fused neighbor pipeline, 8-point tile =============
// 512 thr / 8 waves, 16-col strip per wave, 128-row LDS tile. Barriers and
// weight B-loads per point HALVED/QUARTERED vs the 4-point tile; register
// peak ~110 (posr 32 + lg 32 persist; q staged via LDS, not regs).
#define K2_PTS 8
#define K2_R   (K2_PTS * KNB)   // 128 rows

__global__ __launch_bounds__(512, 4) void attn_kernel(
    const float* __restrict__ new_xyz, const float* __restrict__ grouped_xyz,
    const int* __restrict__ grouped_idx,
    const float* __restrict__ dw1, const float* __restrict__ db1,
    const float* __restrict__ db2,
    const float* __restrict__ gb1, const float* __restrict__ gb2,
    const unsigned short* __restrict__ wbf,
    const unsigned short* __restrict__ qws, const unsigned short* __restrict__ kvws,
    float* __restrict__ out)
{
    __shared__ __align__(16) unsigned short X[K2_R * DM];    // 32768 B
    __shared__ __align__(16) unsigned short QB[K2_PTS * DM]; //  2048 B
    __shared__ float REL[K2_R * 3];
    __shared__ int   IDX[K2_R];

    const int tid  = threadIdx.x;
    const int lane = tid & 63;
    const int wave = tid >> 6;          // 0..7
    const int wb16 = wave * 16;
    const int c  = lane & 15;
    const int g  = lane >> 4;
    const int g4 = g * 4;
    const int r0e = tid >> 4;           // 0..31; vector-phase rows r = it*32+r0e
    const int o8  = (tid & 15) * 8;

    const int b   = blockIdx.x / (NPTS / K2_PTS);
    const int m0  = (blockIdx.x % (NPTS / K2_PTS)) * K2_PTS;
    const size_t gp0 = (size_t)b * NPTS + m0;
    const size_t bN  = (size_t)b * NPTS;
    const float SCL = 0.12751743342f;   // 1/sqrt(128) * log2(e)

    const unsigned short* dw2b = wbf + WOFF_DW2;
    const unsigned short* gw1b = wbf + WOFF_GW1;
    const unsigned short* gw2b = wbf + WOFF_GW2;

    // ---- P0: idx + rel (threads 0-127); stage q tile (threads 384-511) ----
    if (tid < K2_R) {
        const int p = tid >> 4, j = tid & 15;
        const size_t m = gp0 + p;
        const int mi = m0 + p;
#pragma unroll
        for (int cc = 0; cc < 3; ++cc)
            REL[tid * 3 + cc] = new_xyz[m * 3 + cc]
                              - grouped_xyz[(((size_t)b * 3 + cc) * NPTS + mi) * KNB + j];
        IDX[tid] = grouped_idx[m * KNB + j];
    } else if (tid >= 384) {
        const int i = tid - 384;                 // 128 octets = 8 rows x 16
        const int r = i >> 4, o = (i & 15) * 8;
        *(bf16x8*)&QB[r * DM + o] = *(const bf16x8*)&qws[(gp0 + r) * DM + o];
    }
    __syncthreads();

    // ---- prefetch k gathers (consumed in P3) ----
    bf16x8 k8[4];
#pragma unroll
    for (int it = 0; it < 4; ++it)
        k8[it] = *(const bf16x8*)&kvws[(bN + IDX[it * 32 + r0e]) * (2 * DM) + o8];

    // ---- P1: relu1 = relu(rel @ dw1.T + db1) -> X (4 octets/thread) ----
    {
        float wr[24], bbv[8];
        const float4* wsrc = (const float4*)&dw1[o8 * 3];
#pragma unroll
        for (int t = 0; t < 6; ++t) ((float4*)wr)[t] = wsrc[t];
        const float4* bsrc = (const float4*)&db1[o8];
        ((float4*)bbv)[0] = bsrc[0];
        ((float4*)bbv)[1] = bsrc[1];
#pragma unroll
        for (int it = 0; it < 4; ++it) {
            const int r = it * 32 + r0e;
            const float rx = REL[r * 3 + 0], ry = REL[r * 3 + 1], rz = REL[r * 3 + 2];
            bf16x8 t;
#pragma unroll
            for (int j = 0; j < 8; ++j) {
                float v = bbv[j];
                v = fmaf(rx, wr[j * 3 + 0], v);
                v = fmaf(ry, wr[j * 3 + 1], v);
                v = fmaf(rz, wr[j * 3 + 2], v);
                t[j] = (short)f2bf(fmaxf(v, 0.f));
            }
            *(bf16x8*)&X[swz(r, o8)] = t;
        }
    }
    __syncthreads();

    // ---- P2: pos = relu1 @ dw2.T + db2 ; f32 persists to P6; bf16 -> X ----
    f32x4 posr[8];
    {
        const float b2v = db2[wb16 + c];
#pragma unroll
        for (int rt = 0; rt < 8; ++rt) posr[rt] = (f32x4)b2v;
    }
    gemm16w(X, dw2b, c, g, wb16, posr);
    __syncthreads();   // drain relu1 reads before overwrite
#pragma unroll
    for (int rt = 0; rt < 8; ++rt)
#pragma unroll
        for (int rg = 0; rg < 4; ++rg)
            X[swz(rt * 16 + g4 + rg, wb16 + c)] = f2bf(posr[rt][rg]);
    __syncthreads();

    // ---- P3: h = q - k + pos -> X (octet-owned, q from QB) ----
#pragma unroll
    for (int it = 0; it < 4; ++it) {
        const int r = it * 32 + r0e;
        const int p = r >> 4;
        const bf16x8 p8 = *(const bf16x8*)&X[swz(r, o8)];
        const bf16x8 q8 = *(const bf16x8*)&QB[p * DM + o8];
        bf16x8 t;
#pragma unroll
        for (int j = 0; j < 8; ++j) {
            const float hv = bf2f((unsigned short)q8[j])
                           - bf2f((unsigned short)k8[it][j])
                           + bf2f((unsigned short)p8[j]);
            t[j] = (short)f2bf(hv);
        }
        *(bf16x8*)&X[swz(r, o8)] = t;
    }
    __syncthreads();

    // ---- P4: g1 = relu(h @ gw1.T + gb1) -> X (drain then write) ----
    {
        f32x4 acc[8];
        const float b1v = gb1[wb16 + c];
#pragma unroll
        for (int rt = 0; rt < 8; ++rt) acc[rt] = (f32x4)b1v;
        gemm16w(X, gw1b, c, g, wb16, acc);
        __syncthreads();   // drain h reads
#pragma unroll
        for (int rt = 0; rt < 8; ++rt)
#pragma unroll
            for (int rg = 0; rg < 4; ++rg)
                X[swz(rt * 16 + g4 + rg, wb16 + c)] = f2bf(fmaxf(acc[rt][rg], 0.f));
    }
    __syncthreads();

    // ---- P5: logits = (g1 @ gw2.T + gb2) * scl (regs) ----
    f32x4 lg[8];
#pragma unroll
    for (int rt = 0; rt < 8; ++rt) lg[rt] = (f32x4)0.f;
    gemm16w(X, gw2b, c, g, wb16, lg);
    {
        const float bb = gb2[wb16 + c];
#pragma unroll
        for (int rt = 0; rt < 8; ++rt)
#pragma unroll
            for (int rg = 0; rg < 4; ++rg)
                lg[rt][rg] = (lg[rt][rg] + bb) * SCL;
    }

    // ---- P6: softmax over 16 neighbors + output reduce ----
#pragma unroll
    for (int rt = 0; rt < 8; ++rt) {
        const int col = wb16 + c;
        f32x4 l = lg[rt];
        float mx = fmaxf(fmaxf(l[0], l[1]), fmaxf(l[2], l[3]));
        mx = fmaxf(mx, __shfl_xor(mx, 16));
        mx = fmaxf(mx, __shfl_xor(mx, 32));
        f32x4 e;
        e[0] = __builtin_amdgcn_exp2f(l[0] - mx);
        e[1] = __builtin_amdgcn_exp2f(l[1] - mx);
        e[2] = __builtin_amdgcn_exp2f(l[2] - mx);
        e[3] = __builtin_amdgcn_exp2f(l[3] - mx);
        float s = e[0] + e[1] + e[2] + e[3];
        s += __shfl_xor(s, 16);
        s += __shfl_xor(s, 32);
        float o = 0.f;
#pragma unroll
        for (int rg = 0; rg < 4; ++rg) {
            const int row = rt * 16 + g4 + rg;
            const float vv = bf2f(kvws[(bN + IDX[row]) * (2 * DM) + DM + col])
                           + posr[rt][rg];
            o = fmaf(e[rg], vv, o);
        }
        o += __shfl_xor(o, 16);
        o += __shfl_xor(o, 32);
        if (g == 0)
            out[(gp0 + rt) * DM + col] = o * __builtin_amdgcn_rcpf(s);
    }
}

// ======================= launch =======================
extern "C" void kernel_launch(void* const* d_in, const int* in_sizes, int n_in,
                              void* d_out, int out_size, void* d_ws, size_t ws_size,
                              hipStream_t stream)
{
    const float* new_xyz     = (const float*)d_in[0];
    const float* grouped_xyz = (const float*)d_in[1];
    const int*   grouped_idx = (const int*)d_in[2];
    const float* features    = (const float*)d_in[3];
    const float* fc1_w = (const float*)d_in[4];
    const float* fc1_b = (const float*)d_in[5];
    const float* wq    = (const float*)d_in[6];
    const float* wk    = (const float*)d_in[7];
    const float* wv    = (const float*)d_in[8];
    const float* dw1   = (const float*)d_in[9];
    const float* db1   = (const float*)d_in[10];
    const float* dw2   = (const float*)d_in[11];
    const float* db2   = (const float*)d_in[12];
    const float* gw1   = (const float*)d_in[13];
    const float* gb1   = (const float*)d_in[14];
    const float* gw2   = (const float*)d_in[15];
    const float* gb2   = (const float*)d_in[16];
    float* out = (float*)d_out;

    unsigned short* ws = (unsigned short*)d_ws;
    const size_t npt = (size_t)BB * NPTS * DM;
    unsigned short* qws  = ws;
    unsigned short* kvws = ws + npt;        // [row][k:128 | v:128]
    unsigned short* wbf  = ws + 3 * npt;

    cvtw_kernel<<<(WTOT + 255) / 256, 256, 0, stream>>>(
        dw2, gw1, gw2, wq, wk, wv, fc1_w, wbf);

    proj_kernel<<<(BB * NPTS) / P_MT, 256, 0, stream>>>(
        features, fc1_b, wbf, qws, kvws);

    attn_kernel<<<(BB * NPTS) / K2_PTS, 512, 0, stream>>>(
        new_xyz, grouped_xyz, grouped_idx,
        dw1, db1, db2, gb1, gb2,
        wbf, qws, kvws, out);
}